// Round 13
// baseline (546.312 us; speedup 1.0000x reference)
//
#include <hip/hip_runtime.h>

typedef __attribute__((ext_vector_type(8))) short bf16x8;
typedef __attribute__((ext_vector_type(4))) float f32x4;
typedef __attribute__((ext_vector_type(4))) unsigned short u16x4;
typedef unsigned short ushort_t;
typedef unsigned int uint32;

constexpr int B_ = 2, S_ = 2048, D_ = 1024, H_ = 16, DH_ = 64;
constexpr int M_TOK = B_ * S_;    // 4096
constexpr int N_QKV = 3 * D_;     // 3072

#define DEV __device__ __forceinline__

DEV ushort_t f2bf(float f) {
  uint32 u = __builtin_bit_cast(uint32, f);
  u += 0x7fffu + ((u >> 16) & 1u);
  return (ushort_t)(u >> 16);
}

DEV float bf2f(ushort_t u) {
  uint32 x = ((uint32)u) << 16;
  return __builtin_bit_cast(float, x);
}

DEV void gll16(const void* g, void* l) {
  __builtin_amdgcn_global_load_lds(
      (const __attribute__((address_space(1))) void*)g,
      (__attribute__((address_space(3))) void*)l, 16, 0, 0);
}

// ---------------- K0a: Q fp32 -> bf16 ----------------
__global__ __launch_bounds__(256) void k_cvt_q(const float* __restrict__ in,
                                               ushort_t* __restrict__ out) {
  int i = (blockIdx.x * 256 + threadIdx.x) * 4;
  float4 v = *(const float4*)(in + i);
  u16x4 o;
  o.x = f2bf(v.x); o.y = f2bf(v.y); o.z = f2bf(v.z); o.w = f2bf(v.w);
  *(u16x4*)(out + i) = o;
}

// ---------------- K0b: transpose + convert W [R][C] fp32 -> [C][R] bf16 ----
__global__ __launch_bounds__(256) void k_transpose_cvt(const float* __restrict__ in,
                                                       ushort_t* __restrict__ out,
                                                       int R, int C) {
  __shared__ float t[32][33];
  int bx = blockIdx.x, by = blockIdx.y;
  int tx = threadIdx.x & 31, ty = threadIdx.x >> 5;  // ty 0..7
#pragma unroll
  for (int i = 0; i < 4; ++i) {
    int r = by * 32 + ty + i * 8;
    t[ty + i * 8][tx] = in[(size_t)r * C + bx * 32 + tx];
  }
  __syncthreads();
#pragma unroll
  for (int i = 0; i < 4; ++i) {
    int orow = bx * 32 + ty + i * 8;  // output row = original col
    int ocol = by * 32 + tx;          // output col = original row
    out[(size_t)orow * R + ocol] = f2bf(t[tx][ty + i * 8]);
  }
}

// ---------------- K1: QKV GEMM (bf16 MFMA) + scatter epilogue -------------
__global__ __launch_bounds__(256) void k_gemm_qkv(
    const ushort_t* __restrict__ A,   // [4096][1024]
    const ushort_t* __restrict__ Bt,  // [3072][1024]
    const float* __restrict__ bias,   // [3072]
    ushort_t* __restrict__ qh,        // [B][H][S][64]
    ushort_t* __restrict__ kh,        // [B][H][S][64]
    ushort_t* __restrict__ vT) {      // [B][H][64][S]
  constexpr int K = 1024;
  __shared__ ushort_t lA[128 * 32];
  __shared__ ushort_t lB[128 * 32];
  const int t = threadIdx.x, lane = t & 63, w = t >> 6;
  const int wm = w >> 1, wn = w & 1;
  const int bm = blockIdx.x & 31, bn = blockIdx.x >> 5;  // 32 x 24

  f32x4 acc[4][4];
#pragma unroll
  for (int i = 0; i < 4; ++i)
#pragma unroll
    for (int j = 0; j < 4; ++j) acc[i][j] = f32x4{0.f, 0.f, 0.f, 0.f};

  const int srow = t >> 2;        // 0..63
  const int scol = (t & 3) * 8;   // 0,8,16,24
  for (int k0 = 0; k0 < K; k0 += 32) {
    __syncthreads();
    gll16(A + (size_t)(bm * 128 + srow) * K + k0 + scol, lA + srow * 32 + scol);
    gll16(A + (size_t)(bm * 128 + 64 + srow) * K + k0 + scol, lA + (64 + srow) * 32 + scol);
    gll16(Bt + (size_t)(bn * 128 + srow) * K + k0 + scol, lB + srow * 32 + scol);
    gll16(Bt + (size_t)(bn * 128 + 64 + srow) * K + k0 + scol, lB + (64 + srow) * 32 + scol);
    asm volatile("s_waitcnt vmcnt(0)" ::: "memory");
    __syncthreads();
    bf16x8 af[4], bfr[4];
#pragma unroll
    for (int i = 0; i < 4; ++i)
      af[i] = *(const bf16x8*)(lA + (wm * 64 + i * 16 + (lane & 15)) * 32 + (lane >> 4) * 8);
#pragma unroll
    for (int j = 0; j < 4; ++j)
      bfr[j] = *(const bf16x8*)(lB + (wn * 64 + j * 16 + (lane & 15)) * 32 + (lane >> 4) * 8);
#pragma unroll
    for (int i = 0; i < 4; ++i)
#pragma unroll
      for (int j = 0; j < 4; ++j)
        acc[i][j] = __builtin_amdgcn_mfma_f32_16x16x32_bf16(af[i], bfr[j], acc[i][j], 0, 0, 0);
  }
#pragma unroll
  for (int i = 0; i < 4; ++i) {
#pragma unroll
    for (int j = 0; j < 4; ++j) {
#pragma unroll
      for (int p = 0; p < 4; ++p) {
        int row = bm * 128 + wm * 64 + i * 16 + (lane >> 4) * 4 + p;  // token
        int col = bn * 128 + wn * 64 + j * 16 + (lane & 15);          // 0..3071
        float v = acc[i][j][p] + bias[col];
        ushort_t bv = f2bf(v);
        int b = row >> 11, s = row & (S_ - 1);
        int h = col / 192, r = col - h * 192;
        size_t bh = (size_t)(b * H_ + h);
        if (r < 64)
          qh[(bh * S_ + s) * 64 + r] = bv;
        else if (r < 128)
          kh[(bh * S_ + s) * 64 + (r - 64)] = bv;
        else
          vT[(bh * 64 + (r - 128)) * S_ + s] = bv;
      }
    }
  }
}

// ---------------- K2: persistent fused scores + partial PV ----------------
// Grid 512 = 32 bh x 4 ct x 4 rt-groups (2 blocks/CU, one round). Each block
// stages its (bh, ct) K slice ONCE, then sweeps 8 rt tiles = 32 uniform
// chunks; prev pipeline never drains across tiles. Q fragments double-
// buffered (explicit A/B names), prefetched at chunk 3 BEFORE the next prev
// issue so the QK wait never drains younger HBM loads. Chunk body = R8.
__global__ __launch_bounds__(256, 2) void k_scores_pv(
    const ushort_t* __restrict__ qhp,  // [BH][S][64]
    const ushort_t* __restrict__ khp,  // [BH][S][64]
    const ushort_t* __restrict__ vT,   // [BH][64][S]
    const float* __restrict__ prev,    // [BH][S][S]
    float* __restrict__ scores,        // [BH][S][S]
    float* __restrict__ pstats,        // [BH][S][4][2]
    ushort_t* __restrict__ Opart) {    // [BH][S][4][64] bf16
  __shared__ ushort_t lK[512 * 64];    // 64 KB
  __shared__ ushort_t Plds[4][2048];   // 16 KB (per-wave 4 KB P tile)
  const int t = threadIdx.x, lane = t & 63, w = t >> 6;
  int idx = (int)blockIdx.x;
  idx = (idx & 7) * 64 + (idx >> 3);   // bijective XCD swizzle (512 = 8*64)
  const int bh = idx >> 4, ct = (idx >> 2) & 3, rtg = idx & 3;
  const int kt0 = ct * 512;
  const int lo = lane & 15, hi = lane >> 4;

  const ushort_t* qbase = qhp + (size_t)bh * S_ * 64;
  const ushort_t* kb = khp + ((size_t)bh * S_ + kt0) * 64;
  const ushort_t* vb = vT + (size_t)bh * 64 * S_ + kt0;
  const float* prev_base = prev + (size_t)bh * S_ * S_ + kt0;
  float* scores_base = scores + (size_t)bh * S_ * S_ + kt0;

  // ---- stage K 512x64 bf16 -> LDS once (R8-validated pattern) ----
#pragma unroll
  for (int i = 0; i < 16; ++i) {
    int u = i * 256 + t;            // 16-byte unit index
    int r = u >> 3;                 // k row (0..511)
    int s = (u & 7) * 16;           // byte within row
    int cb = s ^ ((r & 7) << 4);    // swizzled source byte
    gll16(kb + (size_t)r * 64 + cb / 2, (ushort_t*)lK + u * 8);
  }
  // ---- Q frags for rt 0 + first prev tile, before the one-time drain ----
  const int row00 = rtg * 512 + w * 16;
  bf16x8 qfA0 = *(const bf16x8*)(qbase + (row00 + lo) * 64 + hi * 8);
  bf16x8 qfA1 = *(const bf16x8*)(qbase + (row00 + lo) * 64 + 32 + hi * 8);
  bf16x8 qfB0, qfB1;
  float4 pcur[8];
#pragma unroll
  for (int kf = 0; kf < 8; ++kf)
    pcur[kf] = *(const float4*)(prev_base + (size_t)(row00 + lo) * S_ + kf * 16 + hi * 4);
  asm volatile("s_waitcnt vmcnt(0)" ::: "memory");
  __syncthreads();

  const int swz = (lo & 7) << 4;
  const char* lkb = (const char*)lK;
  char* pw = (char*)&Plds[w][0];

#define RT_BODY(QF0, QF1, NQF0, NQF1, RT, LAST)                               \
  {                                                                           \
    const int row0 = rtg * 512 + (RT) * 64 + w * 16;                          \
    const float* pb = prev_base + (size_t)(row0 + lo) * S_;                   \
    float* sb = scores_base + (size_t)(row0 + lo) * S_;                       \
    f32x4 acco[4];                                                            \
    _Pragma("unroll") for (int dn = 0; dn < 4; ++dn)                          \
        acco[dn] = f32x4{0.f, 0.f, 0.f, 0.f};                                 \
    float m_run = -1e30f, l_run = 0.f;                                        \
    _Pragma("unroll") for (int c = 0; c < 4; ++c) {                           \
      bf16x8 vf[4][4];                                                        \
      _Pragma("unroll") for (int kc = 0; kc < 4; ++kc)                        \
          _Pragma("unroll") for (int dn = 0; dn < 4; ++dn)                    \
              vf[kc][dn] = *(const bf16x8*)(vb + (size_t)(dn * 16 + lo) * S_ +\
                                            c * 128 + kc * 32 + hi * 8);      \
      if (c == 3 && !(LAST)) { /* Q(rt+1), older than next prev issue */      \
        NQF0 = *(const bf16x8*)(qbase + (row0 + 64 + lo) * 64 + hi * 8);      \
        NQF1 = *(const bf16x8*)(qbase + (row0 + 64 + lo) * 64 + 32 + hi * 8); \
      }                                                                       \
      float4 pnext[8];                                                        \
      if (c < 3) {                                                            \
        _Pragma("unroll") for (int kf = 0; kf < 8; ++kf)                      \
            pnext[kf] = *(const float4*)(pb + (c + 1) * 128 + kf * 16 + hi * 4);\
      } else if (!(LAST)) {                                                   \
        _Pragma("unroll") for (int kf = 0; kf < 8; ++kf)                      \
            pnext[kf] = *(const float4*)(pb + 64 * S_ + kf * 16 + hi * 4);    \
      }                                                                       \
      f32x4 acc[8];                                                           \
      _Pragma("unroll") for (int kf = 0; kf < 8; ++kf)                        \
          acc[kf] = f32x4{0.f, 0.f, 0.f, 0.f};                                \
      _Pragma("unroll") for (int kf = 0; kf < 8; ++kf) {                      \
        int krow = c * 128 + kf * 16 + lo;                                    \
        bf16x8 k0 = *(const bf16x8*)(lkb + krow * 128 + ((hi * 16) ^ swz));   \
        bf16x8 k1 = *(const bf16x8*)(lkb + krow * 128 + ((64 + hi * 16) ^ swz));\
        acc[kf] = __builtin_amdgcn_mfma_f32_16x16x32_bf16(k0, QF0, acc[kf], 0, 0, 0);\
        acc[kf] = __builtin_amdgcn_mfma_f32_16x16x32_bf16(k1, QF1, acc[kf], 0, 0, 0);\
      }                                                                       \
      float tmax = -1e30f;                                                    \
      _Pragma("unroll") for (int kf = 0; kf < 8; ++kf) {                      \
        acc[kf][0] = acc[kf][0] * 0.125f + pcur[kf].x;                        \
        acc[kf][1] = acc[kf][1] * 0.125f + pcur[kf].y;                        \
        acc[kf][2] = acc[kf][2] * 0.125f + pcur[kf].z;                        \
        acc[kf][3] = acc[kf][3] * 0.125f + pcur[kf].w;                        \
        *(float4*)(sb + c * 128 + kf * 16 + hi * 4) =                         \
            float4{acc[kf][0], acc[kf][1], acc[kf][2], acc[kf][3]};           \
        tmax = fmaxf(tmax, fmaxf(fmaxf(acc[kf][0], acc[kf][1]),               \
                                 fmaxf(acc[kf][2], acc[kf][3])));             \
      }                                                                       \
      tmax = fmaxf(tmax, __shfl_xor(tmax, 16));                               \
      tmax = fmaxf(tmax, __shfl_xor(tmax, 32));                               \
      float m_new = fmaxf(m_run, tmax);                                       \
      float fs = __expf(m_run - m_new);                                       \
      float lsum = 0.f;                                                       \
      _Pragma("unroll") for (int kf = 0; kf < 8; ++kf) {                      \
        float e0 = __expf(acc[kf][0] - m_new);                                \
        float e1 = __expf(acc[kf][1] - m_new);                                \
        float e2 = __expf(acc[kf][2] - m_new);                                \
        float e3 = __expf(acc[kf][3] - m_new);                                \
        lsum += (e0 + e1) + (e2 + e3);                                        \
        u16x4 pk;                                                             \
        pk.x = f2bf(e0); pk.y = f2bf(e1); pk.z = f2bf(e2); pk.w = f2bf(e3);   \
        int byte = (lo * 256 + kf * 32 + hi * 8) ^ swz;                       \
        *(u16x4*)(pw + byte) = pk;                                            \
      }                                                                       \
      lsum += __shfl_xor(lsum, 16);                                           \
      lsum += __shfl_xor(lsum, 32);                                           \
      m_run = m_new;                                                          \
      l_run = l_run * fs + lsum;                                              \
      _Pragma("unroll") for (int dn = 0; dn < 4; ++dn)                        \
          _Pragma("unroll") for (int p = 0; p < 4; ++p) acco[dn][p] *= fs;    \
      _Pragma("unroll") for (int kc = 0; kc < 4; ++kc) {                      \
        int byte = (lo * 256 + kc * 64 + hi * 16) ^ swz;                      \
        bf16x8 pa = *(const bf16x8*)(pw + byte);                              \
        _Pragma("unroll") for (int dn = 0; dn < 4; ++dn)                      \
            acco[dn] = __builtin_amdgcn_mfma_f32_16x16x32_bf16(               \
                vf[kc][dn], pa, acco[dn], 0, 0, 0);                           \
      }                                                                       \
      if (c < 3 || !(LAST)) {                                                 \
        _Pragma("unroll") for (int kf = 0; kf < 8; ++kf) pcur[kf] = pnext[kf];\
      }                                                                       \
    }                                                                         \
    ushort_t* ob = Opart + (((size_t)bh * S_ + row0 + lo) * 4 + ct) * 64;     \
    _Pragma("unroll") for (int dn = 0; dn < 4; ++dn) {                        \
      u16x4 ov;                                                               \
      _Pragma("unroll") for (int p = 0; p < 4; ++p) ov[p] = f2bf(acco[dn][p]);\
      *(u16x4*)(ob + dn * 16 + hi * 4) = ov;                                  \
    }                                                                         \
    if (hi == 0)                                                              \
      *(float2*)(pstats + (((size_t)bh * S_ + row0 + lo) * 4 + ct) * 2) =     \
          float2{m_run, l_run};                                               \
  }

  for (int i = 0; i < 3; ++i) {
    RT_BODY(qfA0, qfA1, qfB0, qfB1, 2 * i, false);
    RT_BODY(qfB0, qfB1, qfA0, qfA1, 2 * i + 1, false);
  }
  RT_BODY(qfA0, qfA1, qfB0, qfB1, 6, false);
  RT_BODY(qfB0, qfB1, qfA0, qfA1, 7, true);
#undef RT_BODY
}

// ---------------- K3: combine partial O -> ctx ----------------------------
__global__ __launch_bounds__(256) void k_combine(
    const float* __restrict__ pstats,  // [BH][S][4][2]
    const ushort_t* __restrict__ Opart,// [BH][S][4][64]
    ushort_t* __restrict__ ctx) {      // [M_TOK][D]
  const int t = threadIdx.x;
  const int row = blockIdx.x * 64 + (t >> 2);  // bh*S + s
  const int hi4 = t & 3;
  const int bh = row >> 11, s = row & (S_ - 1);

  const float* ps = pstats + (size_t)row * 8;
  float2 st[4];
#pragma unroll
  for (int i = 0; i < 4; ++i) st[i] = *(const float2*)(ps + i * 2);
  float m = fmaxf(fmaxf(st[0].x, st[1].x), fmaxf(st[2].x, st[3].x));
  float den = 0.f;
#pragma unroll
  for (int i = 0; i < 4; ++i) den += st[i].y * __expf(st[i].x - m);
  float sc[4];
#pragma unroll
  for (int i = 0; i < 4; ++i) sc[i] = __expf(st[i].x - m) / den;

  const ushort_t* ob = Opart + (size_t)row * 256 + hi4 * 16;
  float o[16];
#pragma unroll
  for (int j = 0; j < 16; ++j) o[j] = 0.f;
#pragma unroll
  for (int i = 0; i < 4; ++i) {
    bf16x8 a0 = *(const bf16x8*)(ob + i * 64);
    bf16x8 a1 = *(const bf16x8*)(ob + i * 64 + 8);
#pragma unroll
    for (int j = 0; j < 8; ++j) {
      o[j]     += bf2f((ushort_t)a0[j]) * sc[i];
      o[8 + j] += bf2f((ushort_t)a1[j]) * sc[i];
    }
  }
  const int b = bh >> 4, h = bh & 15;
  ushort_t* cp = ctx + (size_t)(b * S_ + s) * D_ + h * 64 + hi4 * 16;
#pragma unroll
  for (int g = 0; g < 4; ++g) {
    u16x4 ov;
#pragma unroll
    for (int p = 0; p < 4; ++p) ov[p] = f2bf(o[g * 4 + p]);
    *(u16x4*)(cp + g * 4) = ov;
  }
}

// ---------------- K4: output GEMM + bias (fp32 out) -----------------------
__global__ __launch_bounds__(256) void k_gemm_out(
    const ushort_t* __restrict__ A,   // ctx [4096][1024]
    const ushort_t* __restrict__ Bt,  // WoutT [1024][1024]
    const float* __restrict__ bias,   // [1024]
    float* __restrict__ out) {
  constexpr int K = 1024;
  __shared__ ushort_t lA[128 * 32];
  __shared__ ushort_t lB[128 * 32];
  const int t = threadIdx.x, lane = t & 63, w = t >> 6;
  const int wm = w >> 1, wn = w & 1;
  const int bm = blockIdx.x & 31, bn = blockIdx.x >> 5;  // 32 x 8

  f32x4 acc[4][4];
#pragma unroll
  for (int i = 0; i < 4; ++i)
#pragma unroll
    for (int j = 0; j < 4; ++j) acc[i][j] = f32x4{0.f, 0.f, 0.f, 0.f};

  const int srow = t >> 2;
  const int scol = (t & 3) * 8;
  for (int k0 = 0; k0 < K; k0 += 32) {
    __syncthreads();
    gll16(A + (size_t)(bm * 128 + srow) * K + k0 + scol, lA + srow * 32 + scol);
    gll16(A + (size_t)(bm * 128 + 64 + srow) * K + k0 + scol, lA + (64 + srow) * 32 + scol);
    gll16(Bt + (size_t)(bn * 128 + srow) * K + k0 + scol, lB + srow * 32 + scol);
    gll16(Bt + (size_t)(bn * 128 + 64 + srow) * K + k0 + scol, lB + (64 + srow) * 32 + scol);
    asm volatile("s_waitcnt vmcnt(0)" ::: "memory");
    __syncthreads();
    bf16x8 af[4], bfr[4];
#pragma unroll
    for (int i = 0; i < 4; ++i)
      af[i] = *(const bf16x8*)(lA + (wm * 64 + i * 16 + (lane & 15)) * 32 + (lane >> 4) * 8);
#pragma unroll
    for (int j = 0; j < 4; ++j)
      bfr[j] = *(const bf16x8*)(lB + (wn * 64 + j * 16 + (lane & 15)) * 32 + (lane >> 4) * 8);
#pragma unroll
    for (int i = 0; i < 4; ++i)
#pragma unroll
      for (int j = 0; j < 4; ++j)
        acc[i][j] = __builtin_amdgcn_mfma_f32_16x16x32_bf16(af[i], bfr[j], acc[i][j], 0, 0, 0);
  }
#pragma unroll
  for (int i = 0; i < 4; ++i) {
#pragma unroll
    for (int j = 0; j < 4; ++j) {
#pragma unroll
      for (int p = 0; p < 4; ++p) {
        int row = bm * 128 + wm * 64 + i * 16 + (lane >> 4) * 4 + p;
        int col = bn * 128 + wn * 64 + j * 16 + (lane & 15);
        out[(size_t)row * 1024 + col] = acc[i][j][p] + bias[col];
      }
    }
  }
}

extern "C" void kernel_launch(void* const* d_in, const int* in_sizes, int n_in,
                              void* d_out, int out_size, void* d_ws, size_t ws_size,
                              hipStream_t stream) {
  (void)in_sizes; (void)n_in; (void)out_size; (void)ws_size;
  const float* Q     = (const float*)d_in[0];
  const float* prev  = (const float*)d_in[1];
  const float* W_qkv = (const float*)d_in[2];
  const float* b_qkv = (const float*)d_in[3];
  const float* W_out = (const float*)d_in[4];
  const float* b_out = (const float*)d_in[5];
  float* out = (float*)d_out;
  float* scores_out = out + (size_t)M_TOK * D_;  // output first, then scores

  char* ws = (char*)d_ws;
  ushort_t* Qb    = (ushort_t*)(ws + (size_t)0);          // 8 MB (dead after QKV)
  ushort_t* WqkvT = (ushort_t*)(ws + ((size_t)8  << 20)); // 6 MB
  ushort_t* WoutT = (ushort_t*)(ws + ((size_t)14 << 20)); // 2 MB
  ushort_t* qh    = (ushort_t*)(ws + ((size_t)16 << 20)); // 8 MB
  ushort_t* kh    = (ushort_t*)(ws + ((size_t)24 << 20)); // 8 MB
  ushort_t* vT    = (ushort_t*)(ws + ((size_t)32 << 20)); // 8 MB
  ushort_t* ctx   = (ushort_t*)(ws + ((size_t)40 << 20)); // 8 MB
  ushort_t* Opart = (ushort_t*)(ws + ((size_t)48 << 20)); // 32 MB -> 80 MB total
  float*    pstats = (float*)Qb;  // 2 MB, aliases Qb (dead after k_gemm_qkv)

  k_cvt_q<<<4096, 256, 0, stream>>>(Q, Qb);
  k_transpose_cvt<<<dim3(96, 32), 256, 0, stream>>>(W_qkv, WqkvT, 1024, 3072);
  k_transpose_cvt<<<dim3(32, 32), 256, 0, stream>>>(W_out, WoutT, 1024, 1024);
  k_gemm_qkv<<<768, 256, 0, stream>>>(Qb, WqkvT, b_qkv, qh, kh, vT);
  k_scores_pv<<<512, 256, 0, stream>>>(qh, kh, vT, prev, scores_out, pstats, Opart);
  k_combine<<<1024, 256, 0, stream>>>(pstats, Opart, ctx);
  k_gemm_out<<<256, 256, 0, stream>>>(ctx, WoutT, b_out, out);
}

// Round 14
// 415.910 us; speedup vs baseline: 1.3135x; 1.3135x over previous
//
#include <hip/hip_runtime.h>

typedef __attribute__((ext_vector_type(8))) short bf16x8;
typedef __attribute__((ext_vector_type(4))) float f32x4;
typedef __attribute__((ext_vector_type(4))) unsigned short u16x4;
typedef unsigned short ushort_t;
typedef unsigned int uint32;

constexpr int B_ = 2, S_ = 2048, D_ = 1024, H_ = 16, DH_ = 64;
constexpr int M_TOK = B_ * S_;    // 4096
constexpr int N_QKV = 3 * D_;     // 3072

#define DEV __device__ __forceinline__

DEV ushort_t f2bf(float f) {
  uint32 u = __builtin_bit_cast(uint32, f);
  u += 0x7fffu + ((u >> 16) & 1u);
  return (ushort_t)(u >> 16);
}

DEV float bf2f(ushort_t u) {
  uint32 x = ((uint32)u) << 16;
  return __builtin_bit_cast(float, x);
}

DEV void gll16(const void* g, void* l) {
  __builtin_amdgcn_global_load_lds(
      (const __attribute__((address_space(1))) void*)g,
      (__attribute__((address_space(3))) void*)l, 16, 0, 0);
}

// ---------------- K0a: Q fp32 -> bf16 ----------------
__global__ __launch_bounds__(256) void k_cvt_q(const float* __restrict__ in,
                                               ushort_t* __restrict__ out) {
  int i = (blockIdx.x * 256 + threadIdx.x) * 4;
  float4 v = *(const float4*)(in + i);
  u16x4 o;
  o.x = f2bf(v.x); o.y = f2bf(v.y); o.z = f2bf(v.z); o.w = f2bf(v.w);
  *(u16x4*)(out + i) = o;
}

// ---------------- K0b: transpose + convert W [R][C] fp32 -> [C][R] bf16 ----
__global__ __launch_bounds__(256) void k_transpose_cvt(const float* __restrict__ in,
                                                       ushort_t* __restrict__ out,
                                                       int R, int C) {
  __shared__ float t[32][33];
  int bx = blockIdx.x, by = blockIdx.y;
  int tx = threadIdx.x & 31, ty = threadIdx.x >> 5;  // ty 0..7
#pragma unroll
  for (int i = 0; i < 4; ++i) {
    int r = by * 32 + ty + i * 8;
    t[ty + i * 8][tx] = in[(size_t)r * C + bx * 32 + tx];
  }
  __syncthreads();
#pragma unroll
  for (int i = 0; i < 4; ++i) {
    int orow = bx * 32 + ty + i * 8;  // output row = original col
    int ocol = by * 32 + tx;          // output col = original row
    out[(size_t)orow * R + ocol] = f2bf(t[tx][ty + i * 8]);
  }
}

// ---------------- K1: QKV GEMM (bf16 MFMA) + scatter epilogue -------------
__global__ __launch_bounds__(256) void k_gemm_qkv(
    const ushort_t* __restrict__ A,   // [4096][1024]
    const ushort_t* __restrict__ Bt,  // [3072][1024]
    const float* __restrict__ bias,   // [3072]
    ushort_t* __restrict__ qh,        // [B][H][S][64]
    ushort_t* __restrict__ kh,        // [B][H][S][64]
    ushort_t* __restrict__ vT) {      // [B][H][64][S]
  constexpr int K = 1024;
  __shared__ ushort_t lA[128 * 32];
  __shared__ ushort_t lB[128 * 32];
  const int t = threadIdx.x, lane = t & 63, w = t >> 6;
  const int wm = w >> 1, wn = w & 1;
  const int bm = blockIdx.x & 31, bn = blockIdx.x >> 5;  // 32 x 24

  f32x4 acc[4][4];
#pragma unroll
  for (int i = 0; i < 4; ++i)
#pragma unroll
    for (int j = 0; j < 4; ++j) acc[i][j] = f32x4{0.f, 0.f, 0.f, 0.f};

  const int srow = t >> 2;        // 0..63
  const int scol = (t & 3) * 8;   // 0,8,16,24
  for (int k0 = 0; k0 < K; k0 += 32) {
    __syncthreads();
    gll16(A + (size_t)(bm * 128 + srow) * K + k0 + scol, lA + srow * 32 + scol);
    gll16(A + (size_t)(bm * 128 + 64 + srow) * K + k0 + scol, lA + (64 + srow) * 32 + scol);
    gll16(Bt + (size_t)(bn * 128 + srow) * K + k0 + scol, lB + srow * 32 + scol);
    gll16(Bt + (size_t)(bn * 128 + 64 + srow) * K + k0 + scol, lB + (64 + srow) * 32 + scol);
    asm volatile("s_waitcnt vmcnt(0)" ::: "memory");
    __syncthreads();
    bf16x8 af[4], bfr[4];
#pragma unroll
    for (int i = 0; i < 4; ++i)
      af[i] = *(const bf16x8*)(lA + (wm * 64 + i * 16 + (lane & 15)) * 32 + (lane >> 4) * 8);
#pragma unroll
    for (int j = 0; j < 4; ++j)
      bfr[j] = *(const bf16x8*)(lB + (wn * 64 + j * 16 + (lane & 15)) * 32 + (lane >> 4) * 8);
#pragma unroll
    for (int i = 0; i < 4; ++i)
#pragma unroll
      for (int j = 0; j < 4; ++j)
        acc[i][j] = __builtin_amdgcn_mfma_f32_16x16x32_bf16(af[i], bfr[j], acc[i][j], 0, 0, 0);
  }
#pragma unroll
  for (int i = 0; i < 4; ++i) {
#pragma unroll
    for (int j = 0; j < 4; ++j) {
#pragma unroll
      for (int p = 0; p < 4; ++p) {
        int row = bm * 128 + wm * 64 + i * 16 + (lane >> 4) * 4 + p;  // token
        int col = bn * 128 + wn * 64 + j * 16 + (lane & 15);          // 0..3071
        float v = acc[i][j][p] + bias[col];
        ushort_t bv = f2bf(v);
        int b = row >> 11, s = row & (S_ - 1);
        int h = col / 192, r = col - h * 192;
        size_t bh = (size_t)(b * H_ + h);
        if (r < 64)
          qh[(bh * S_ + s) * 64 + r] = bv;
        else if (r < 128)
          kh[(bh * S_ + s) * 64 + (r - 64)] = bv;
        else
          vT[(bh * 64 + (r - 128)) * S_ + s] = bv;
      }
    }
  }
}

// ---------------- K2: fused scores + partial PV (R8-validated) ------------
// Block = 64 rows x 512 cols (4 chunks of 128), K staged once to LDS
// (XOR-swizzled src, linear dest). Per chunk, queue order: V(c) [L2, older]
// -> prev(c+1) [HBM, youngest] -> QK^T (LDS) -> consume prev(c) [oldest,
// retires nothing else] -> stats/exp/P->LDS -> PV MFMA (waits V(c);
// prev(c+1)+stores stay in flight). Writes scores, per-(row,ct) partial O
// (bf16, unnormalized wrt m_run) and (m,l) stats.
__global__ __launch_bounds__(256, 2) void k_scores_pv(
    const ushort_t* __restrict__ qhp,  // [BH][S][64]
    const ushort_t* __restrict__ khp,  // [BH][S][64]
    const ushort_t* __restrict__ vT,   // [BH][64][S]
    const float* __restrict__ prev,    // [BH][S][S]
    float* __restrict__ scores,        // [BH][S][S]
    float* __restrict__ pstats,        // [BH][S][4][2]
    ushort_t* __restrict__ Opart) {    // [BH][S][4][64] bf16
  __shared__ ushort_t lK[512 * 64];    // 64 KB
  __shared__ ushort_t Plds[4][2048];   // 16 KB (per-wave 4 KB P tile)
  const int t = threadIdx.x, lane = t & 63, w = t >> 6;
  int idx = (int)blockIdx.x;
  idx = (idx & 7) * 512 + (idx >> 3);  // bijective XCD swizzle (4096 = 8*512)
  const int rt = idx & 31, ct = (idx >> 5) & 3, bh = idx >> 7;
  const int row0 = rt * 64 + w * 16;
  const int kt0 = ct * 512;
  const int lo = lane & 15, hi = lane >> 4;

  const ushort_t* qb = qhp + ((size_t)bh * S_ + row0) * 64;
  const ushort_t* kb = khp + ((size_t)bh * S_ + kt0) * 64;
  const ushort_t* vb = vT + (size_t)bh * 64 * S_ + kt0;
  const float* pb = prev + (size_t)bh * S_ * S_ + (size_t)(row0 + lo) * S_ + kt0;
  float* sb = scores + (size_t)bh * S_ * S_ + (size_t)(row0 + lo) * S_ + kt0;

  // Q B-fragments (q = lo)
  bf16x8 qf0 = *(const bf16x8*)(qb + lo * 64 + hi * 8);
  bf16x8 qf1 = *(const bf16x8*)(qb + lo * 64 + 32 + hi * 8);

  // ---- stage K 512x64 bf16 -> LDS (swizzled src, linear dest) ----
#pragma unroll
  for (int i = 0; i < 16; ++i) {
    int u = i * 256 + t;            // 16-byte unit index
    int r = u >> 3;                 // k row (0..511)
    int s = (u & 7) * 16;           // byte within row
    int cb = s ^ ((r & 7) << 4);    // swizzled source byte
    gll16(kb + (size_t)r * 64 + cb / 2, (ushort_t*)lK + u * 8);
  }
  // ---- issue chunk-0 prev loads before the one-time drain ----
  float4 pcur[8];
#pragma unroll
  for (int kf = 0; kf < 8; ++kf)
    pcur[kf] = *(const float4*)(pb + kf * 16 + hi * 4);
  asm volatile("s_waitcnt vmcnt(0)" ::: "memory");
  __syncthreads();

  const int swz = (lo & 7) << 4;
  const char* lkb = (const char*)lK;
  char* pw = (char*)&Plds[w][0];

  f32x4 acco[4];  // acco[dn][p] = O[d = dn*16 + hi*4 + p][q = lo]
#pragma unroll
  for (int dn = 0; dn < 4; ++dn) acco[dn] = f32x4{0.f, 0.f, 0.f, 0.f};
  float m_run = -1e30f, l_run = 0.f;

  for (int c = 0; c < 4; ++c) {
    // ---- V(c) loads (L2; issued BEFORE prev(c+1) => older in queue) ----
    bf16x8 vf[4][4];
#pragma unroll
    for (int kc = 0; kc < 4; ++kc)
#pragma unroll
      for (int dn = 0; dn < 4; ++dn)
        vf[kc][dn] = *(const bf16x8*)(vb + (size_t)(dn * 16 + lo) * S_ +
                                      c * 128 + kc * 32 + hi * 8);
    // ---- issue prev(c+1) (HBM, youngest) ----
    float4 pnext[8];
    if (c < 3) {
#pragma unroll
      for (int kf = 0; kf < 8; ++kf)
        pnext[kf] = *(const float4*)(pb + (c + 1) * 128 + kf * 16 + hi * 4);
    }
    // ---- QK^T from LDS (lgkmcnt only) ----
    f32x4 acc[8];
#pragma unroll
    for (int kf = 0; kf < 8; ++kf) acc[kf] = f32x4{0.f, 0.f, 0.f, 0.f};
#pragma unroll
    for (int kf = 0; kf < 8; ++kf) {
      int krow = c * 128 + kf * 16 + lo;
      bf16x8 k0 = *(const bf16x8*)(lkb + krow * 128 + ((hi * 16) ^ swz));
      bf16x8 k1 = *(const bf16x8*)(lkb + krow * 128 + ((64 + hi * 16) ^ swz));
      acc[kf] = __builtin_amdgcn_mfma_f32_16x16x32_bf16(k0, qf0, acc[kf], 0, 0, 0);
      acc[kf] = __builtin_amdgcn_mfma_f32_16x16x32_bf16(k1, qf1, acc[kf], 0, 0, 0);
    }
    // ---- consume prev(c) (oldest; retires nothing else); store scores ----
    float tmax = -1e30f;
#pragma unroll
    for (int kf = 0; kf < 8; ++kf) {
      acc[kf][0] = acc[kf][0] * 0.125f + pcur[kf].x;
      acc[kf][1] = acc[kf][1] * 0.125f + pcur[kf].y;
      acc[kf][2] = acc[kf][2] * 0.125f + pcur[kf].z;
      acc[kf][3] = acc[kf][3] * 0.125f + pcur[kf].w;
      *(float4*)(sb + c * 128 + kf * 16 + hi * 4) =
          float4{acc[kf][0], acc[kf][1], acc[kf][2], acc[kf][3]};
      tmax = fmaxf(tmax, fmaxf(fmaxf(acc[kf][0], acc[kf][1]), fmaxf(acc[kf][2], acc[kf][3])));
    }
    // ---- online stats + P pack into per-wave LDS ----
    tmax = fmaxf(tmax, __shfl_xor(tmax, 16));
    tmax = fmaxf(tmax, __shfl_xor(tmax, 32));
    float m_new = fmaxf(m_run, tmax);
    float fs = __expf(m_run - m_new);
    float lsum = 0.f;
#pragma unroll
    for (int kf = 0; kf < 8; ++kf) {
      float e0 = __expf(acc[kf][0] - m_new);
      float e1 = __expf(acc[kf][1] - m_new);
      float e2 = __expf(acc[kf][2] - m_new);
      float e3 = __expf(acc[kf][3] - m_new);
      lsum += (e0 + e1) + (e2 + e3);
      u16x4 pk;
      pk.x = f2bf(e0); pk.y = f2bf(e1); pk.z = f2bf(e2); pk.w = f2bf(e3);
      int byte = (lo * 256 + kf * 32 + hi * 8) ^ swz;
      *(u16x4*)(pw + byte) = pk;
    }
    lsum += __shfl_xor(lsum, 16);
    lsum += __shfl_xor(lsum, 32);
    m_run = m_new;
    l_run = l_run * fs + lsum;
    // ---- rescale acco (q = lo: lane-local factor) ----
#pragma unroll
    for (int dn = 0; dn < 4; ++dn)
#pragma unroll
      for (int p = 0; p < 4; ++p) acco[dn][p] *= fs;
    // ---- PV: A = V frag, B = P from LDS; waits V(c) only ----
#pragma unroll
    for (int kc = 0; kc < 4; ++kc) {
      int byte = (lo * 256 + kc * 64 + hi * 16) ^ swz;
      bf16x8 pa = *(const bf16x8*)(pw + byte);
#pragma unroll
      for (int dn = 0; dn < 4; ++dn)
        acco[dn] = __builtin_amdgcn_mfma_f32_16x16x32_bf16(vf[kc][dn], pa, acco[dn], 0, 0, 0);
    }
    if (c < 3) {
#pragma unroll
      for (int kf = 0; kf < 8; ++kf) pcur[kf] = pnext[kf];
    }
  }
  // ---- epilogue: partial O (bf16) + (m, l) stats ----
  ushort_t* ob = Opart + (((size_t)bh * S_ + row0 + lo) * 4 + ct) * 64;
#pragma unroll
  for (int dn = 0; dn < 4; ++dn) {
    u16x4 ov;
#pragma unroll
    for (int p = 0; p < 4; ++p) ov[p] = f2bf(acco[dn][p]);
    *(u16x4*)(ob + dn * 16 + hi * 4) = ov;
  }
  if (hi == 0)
    *(float2*)(pstats + (((size_t)bh * S_ + row0 + lo) * 4 + ct) * 2) =
        float2{m_run, l_run};
}

// ---------------- K3: combine partial O -> ctx ----------------------------
__global__ __launch_bounds__(256) void k_combine(
    const float* __restrict__ pstats,  // [BH][S][4][2]
    const ushort_t* __restrict__ Opart,// [BH][S][4][64]
    ushort_t* __restrict__ ctx) {      // [M_TOK][D]
  const int t = threadIdx.x;
  const int row = blockIdx.x * 64 + (t >> 2);  // bh*S + s
  const int hi4 = t & 3;
  const int bh = row >> 11, s = row & (S_ - 1);

  const float* ps = pstats + (size_t)row * 8;
  float2 st[4];
#pragma unroll
  for (int i = 0; i < 4; ++i) st[i] = *(const float2*)(ps + i * 2);
  float m = fmaxf(fmaxf(st[0].x, st[1].x), fmaxf(st[2].x, st[3].x));
  float den = 0.f;
#pragma unroll
  for (int i = 0; i < 4; ++i) den += st[i].y * __expf(st[i].x - m);
  float sc[4];
#pragma unroll
  for (int i = 0; i < 4; ++i) sc[i] = __expf(st[i].x - m) / den;

  const ushort_t* ob = Opart + (size_t)row * 256 + hi4 * 16;
  float o[16];
#pragma unroll
  for (int j = 0; j < 16; ++j) o[j] = 0.f;
#pragma unroll
  for (int i = 0; i < 4; ++i) {
    bf16x8 a0 = *(const bf16x8*)(ob + i * 64);
    bf16x8 a1 = *(const bf16x8*)(ob + i * 64 + 8);
#pragma unroll
    for (int j = 0; j < 8; ++j) {
      o[j]     += bf2f((ushort_t)a0[j]) * sc[i];
      o[8 + j] += bf2f((ushort_t)a1[j]) * sc[i];
    }
  }
  const int b = bh >> 4, h = bh & 15;
  ushort_t* cp = ctx + (size_t)(b * S_ + s) * D_ + h * 64 + hi4 * 16;
#pragma unroll
  for (int g = 0; g < 4; ++g) {
    u16x4 ov;
#pragma unroll
    for (int p = 0; p < 4; ++p) ov[p] = f2bf(o[g * 4 + p]);
    *(u16x4*)(cp + g * 4) = ov;
  }
}

// ---------------- K4: output GEMM + bias (fp32 out) -----------------------
__global__ __launch_bounds__(256) void k_gemm_out(
    const ushort_t* __restrict__ A,   // ctx [4096][1024]
    const ushort_t* __restrict__ Bt,  // WoutT [1024][1024]
    const float* __restrict__ bias,   // [1024]
    float* __restrict__ out) {
  constexpr int K = 1024;
  __shared__ ushort_t lA[128 * 32];
  __shared__ ushort_t lB[128 * 32];
  const int t = threadIdx.x, lane = t & 63, w = t >> 6;
  const int wm = w >> 1, wn = w & 1;
  const int bm = blockIdx.x & 31, bn = blockIdx.x >> 5;  // 32 x 8

  f32x4 acc[4][4];
#pragma unroll
  for (int i = 0; i < 4; ++i)
#pragma unroll
    for (int j = 0; j < 4; ++j) acc[i][j] = f32x4{0.f, 0.f, 0.f, 0.f};

  const int srow = t >> 2;
  const int scol = (t & 3) * 8;
  for (int k0 = 0; k0 < K; k0 += 32) {
    __syncthreads();
    gll16(A + (size_t)(bm * 128 + srow) * K + k0 + scol, lA + srow * 32 + scol);
    gll16(A + (size_t)(bm * 128 + 64 + srow) * K + k0 + scol, lA + (64 + srow) * 32 + scol);
    gll16(Bt + (size_t)(bn * 128 + srow) * K + k0 + scol, lB + srow * 32 + scol);
    gll16(Bt + (size_t)(bn * 128 + 64 + srow) * K + k0 + scol, lB + (64 + srow) * 32 + scol);
    asm volatile("s_waitcnt vmcnt(0)" ::: "memory");
    __syncthreads();
    bf16x8 af[4], bfr[4];
#pragma unroll
    for (int i = 0; i < 4; ++i)
      af[i] = *(const bf16x8*)(lA + (wm * 64 + i * 16 + (lane & 15)) * 32 + (lane >> 4) * 8);
#pragma unroll
    for (int j = 0; j < 4; ++j)
      bfr[j] = *(const bf16x8*)(lB + (wn * 64 + j * 16 + (lane & 15)) * 32 + (lane >> 4) * 8);
#pragma unroll
    for (int i = 0; i < 4; ++i)
#pragma unroll
      for (int j = 0; j < 4; ++j)
        acc[i][j] = __builtin_amdgcn_mfma_f32_16x16x32_bf16(af[i], bfr[j], acc[i][j], 0, 0, 0);
  }
#pragma unroll
  for (int i = 0; i < 4; ++i) {
#pragma unroll
    for (int j = 0; j < 4; ++j) {
#pragma unroll
      for (int p = 0; p < 4; ++p) {
        int row = bm * 128 + wm * 64 + i * 16 + (lane >> 4) * 4 + p;
        int col = bn * 128 + wn * 64 + j * 16 + (lane & 15);
        out[(size_t)row * 1024 + col] = acc[i][j][p] + bias[col];
      }
    }
  }
}

extern "C" void kernel_launch(void* const* d_in, const int* in_sizes, int n_in,
                              void* d_out, int out_size, void* d_ws, size_t ws_size,
                              hipStream_t stream) {
  (void)in_sizes; (void)n_in; (void)out_size; (void)ws_size;
  const float* Q     = (const float*)d_in[0];
  const float* prev  = (const float*)d_in[1];
  const float* W_qkv = (const float*)d_in[2];
  const float* b_qkv = (const float*)d_in[3];
  const float* W_out = (const float*)d_in[4];
  const float* b_out = (const float*)d_in[5];
  float* out = (float*)d_out;
  float* scores_out = out + (size_t)M_TOK * D_;  // output first, then scores

  char* ws = (char*)d_ws;
  ushort_t* Qb    = (ushort_t*)(ws + (size_t)0);          // 8 MB (dead after QKV)
  ushort_t* WqkvT = (ushort_t*)(ws + ((size_t)8  << 20)); // 6 MB
  ushort_t* WoutT = (ushort_t*)(ws + ((size_t)14 << 20)); // 2 MB
  ushort_t* qh    = (ushort_t*)(ws + ((size_t)16 << 20)); // 8 MB
  ushort_t* kh    = (ushort_t*)(ws + ((size_t)24 << 20)); // 8 MB
  ushort_t* vT    = (ushort_t*)(ws + ((size_t)32 << 20)); // 8 MB
  ushort_t* ctx   = (ushort_t*)(ws + ((size_t)40 << 20)); // 8 MB
  ushort_t* Opart = (ushort_t*)(ws + ((size_t)48 << 20)); // 32 MB -> 80 MB total
  float*    pstats = (float*)Qb;  // 2 MB, aliases Qb (dead after k_gemm_qkv)

  k_cvt_q<<<4096, 256, 0, stream>>>(Q, Qb);
  k_transpose_cvt<<<dim3(96, 32), 256, 0, stream>>>(W_qkv, WqkvT, 1024, 3072);
  k_transpose_cvt<<<dim3(32, 32), 256, 0, stream>>>(W_out, WoutT, 1024, 1024);
  k_gemm_qkv<<<768, 256, 0, stream>>>(Qb, WqkvT, b_qkv, qh, kh, vT);
  k_scores_pv<<<4096, 256, 0, stream>>>(qh, kh, vT, prev, scores_out, pstats, Opart);
  k_combine<<<1024, 256, 0, stream>>>(pstats, Opart, ctx);
  k_gemm_out<<<256, 256, 0, stream>>>(ctx, WoutT, b_out, out);
}

// Round 15
// 395.332 us; speedup vs baseline: 1.3819x; 1.0521x over previous
//
#include <hip/hip_runtime.h>

typedef __attribute__((ext_vector_type(8))) short bf16x8;
typedef __attribute__((ext_vector_type(4))) float f32x4;
typedef __attribute__((ext_vector_type(4))) unsigned short u16x4;
typedef unsigned short ushort_t;
typedef unsigned int uint32;

constexpr int B_ = 2, S_ = 2048, D_ = 1024, H_ = 16, DH_ = 64;
constexpr int M_TOK = B_ * S_;    // 4096
constexpr int N_QKV = 3 * D_;     // 3072

#define DEV __device__ __forceinline__

DEV ushort_t f2bf(float f) {
  uint32 u = __builtin_bit_cast(uint32, f);
  u += 0x7fffu + ((u >> 16) & 1u);
  return (ushort_t)(u >> 16);
}

DEV float bf2f(ushort_t u) {
  uint32 x = ((uint32)u) << 16;
  return __builtin_bit_cast(float, x);
}

DEV void gll16(const void* g, void* l) {
  __builtin_amdgcn_global_load_lds(
      (const __attribute__((address_space(1))) void*)g,
      (__attribute__((address_space(3))) void*)l, 16, 0, 0);
}

// ---------------- K0a: Q fp32 -> bf16 ----------------
__global__ __launch_bounds__(256) void k_cvt_q(const float* __restrict__ in,
                                               ushort_t* __restrict__ out) {
  int i = (blockIdx.x * 256 + threadIdx.x) * 4;
  float4 v = *(const float4*)(in + i);
  u16x4 o;
  o.x = f2bf(v.x); o.y = f2bf(v.y); o.z = f2bf(v.z); o.w = f2bf(v.w);
  *(u16x4*)(out + i) = o;
}

// ---------------- K0b: transpose + convert W [R][C] fp32 -> [C][R] bf16 ----
__global__ __launch_bounds__(256) void k_transpose_cvt(const float* __restrict__ in,
                                                       ushort_t* __restrict__ out,
                                                       int R, int C) {
  __shared__ float t[32][33];
  int bx = blockIdx.x, by = blockIdx.y;
  int tx = threadIdx.x & 31, ty = threadIdx.x >> 5;  // ty 0..7
#pragma unroll
  for (int i = 0; i < 4; ++i) {
    int r = by * 32 + ty + i * 8;
    t[ty + i * 8][tx] = in[(size_t)r * C + bx * 32 + tx];
  }
  __syncthreads();
#pragma unroll
  for (int i = 0; i < 4; ++i) {
    int orow = bx * 32 + ty + i * 8;  // output row = original col
    int ocol = by * 32 + tx;          // output col = original row
    out[(size_t)orow * R + ocol] = f2bf(t[tx][ty + i * 8]);
  }
}

// ---------------- K1: QKV GEMM (bf16 MFMA) + scatter epilogue -------------
__global__ __launch_bounds__(256) void k_gemm_qkv(
    const ushort_t* __restrict__ A,   // [4096][1024]
    const ushort_t* __restrict__ Bt,  // [3072][1024]
    const float* __restrict__ bias,   // [3072]
    ushort_t* __restrict__ qh,        // [B][H][S][64]
    ushort_t* __restrict__ kh,        // [B][H][S][64]
    ushort_t* __restrict__ vT) {      // [B][H][64][S]
  constexpr int K = 1024;
  __shared__ ushort_t lA[128 * 32];
  __shared__ ushort_t lB[128 * 32];
  const int t = threadIdx.x, lane = t & 63, w = t >> 6;
  const int wm = w >> 1, wn = w & 1;
  const int bm = blockIdx.x & 31, bn = blockIdx.x >> 5;  // 32 x 24

  f32x4 acc[4][4];
#pragma unroll
  for (int i = 0; i < 4; ++i)
#pragma unroll
    for (int j = 0; j < 4; ++j) acc[i][j] = f32x4{0.f, 0.f, 0.f, 0.f};

  const int srow = t >> 2;        // 0..63
  const int scol = (t & 3) * 8;   // 0,8,16,24
  for (int k0 = 0; k0 < K; k0 += 32) {
    __syncthreads();
    gll16(A + (size_t)(bm * 128 + srow) * K + k0 + scol, lA + srow * 32 + scol);
    gll16(A + (size_t)(bm * 128 + 64 + srow) * K + k0 + scol, lA + (64 + srow) * 32 + scol);
    gll16(Bt + (size_t)(bn * 128 + srow) * K + k0 + scol, lB + srow * 32 + scol);
    gll16(Bt + (size_t)(bn * 128 + 64 + srow) * K + k0 + scol, lB + (64 + srow) * 32 + scol);
    asm volatile("s_waitcnt vmcnt(0)" ::: "memory");
    __syncthreads();
    bf16x8 af[4], bfr[4];
#pragma unroll
    for (int i = 0; i < 4; ++i)
      af[i] = *(const bf16x8*)(lA + (wm * 64 + i * 16 + (lane & 15)) * 32 + (lane >> 4) * 8);
#pragma unroll
    for (int j = 0; j < 4; ++j)
      bfr[j] = *(const bf16x8*)(lB + (wn * 64 + j * 16 + (lane & 15)) * 32 + (lane >> 4) * 8);
#pragma unroll
    for (int i = 0; i < 4; ++i)
#pragma unroll
      for (int j = 0; j < 4; ++j)
        acc[i][j] = __builtin_amdgcn_mfma_f32_16x16x32_bf16(af[i], bfr[j], acc[i][j], 0, 0, 0);
  }
#pragma unroll
  for (int i = 0; i < 4; ++i) {
#pragma unroll
    for (int j = 0; j < 4; ++j) {
#pragma unroll
      for (int p = 0; p < 4; ++p) {
        int row = bm * 128 + wm * 64 + i * 16 + (lane >> 4) * 4 + p;  // token
        int col = bn * 128 + wn * 64 + j * 16 + (lane & 15);          // 0..3071
        float v = acc[i][j][p] + bias[col];
        ushort_t bv = f2bf(v);
        int b = row >> 11, s = row & (S_ - 1);
        int h = col / 192, r = col - h * 192;
        size_t bh = (size_t)(b * H_ + h);
        if (r < 64)
          qh[(bh * S_ + s) * 64 + r] = bv;
        else if (r < 128)
          kh[(bh * S_ + s) * 64 + (r - 64)] = bv;
        else
          vT[(bh * 64 + (r - 128)) * S_ + s] = bv;
      }
    }
  }
}

// ---------------- K2: fused scores + partial PV, 8-wave blocks ------------
// R8 chunk body verbatim; block widened to 8 waves / 128 rows sharing ONE
// 64 KB K stage (K traffic and stage-drain prologues halve). LDS 96 KB ->
// 1 block/CU = 8 waves/CU (same wave count as R8's 2x4). Queue discipline
// per chunk unchanged: V(c) [L2, older] -> prev(c+1) [HBM, youngest] ->
// QK^T (LDS) -> consume prev(c) -> stats/exp/P->LDS -> PV (waits V(c)).
__global__ __launch_bounds__(512, 1) void k_scores_pv(
    const ushort_t* __restrict__ qhp,  // [BH][S][64]
    const ushort_t* __restrict__ khp,  // [BH][S][64]
    const ushort_t* __restrict__ vT,   // [BH][64][S]
    const float* __restrict__ prev,    // [BH][S][S]
    float* __restrict__ scores,        // [BH][S][S]
    float* __restrict__ pstats,        // [BH][S][4][2]
    ushort_t* __restrict__ Opart) {    // [BH][S][4][64] bf16
  __shared__ ushort_t lK[512 * 64];    // 64 KB
  __shared__ ushort_t Plds[8][2048];   // 32 KB (per-wave 4 KB P tile)
  const int t = threadIdx.x, lane = t & 63, w = t >> 6;  // w 0..7
  int idx = (int)blockIdx.x;
  idx = (idx & 7) * 256 + (idx >> 3);  // bijective XCD swizzle (2048 = 8*256)
  const int rt = idx & 15, ct = (idx >> 4) & 3, bh = idx >> 6;
  const int row0 = rt * 128 + w * 16;
  const int kt0 = ct * 512;
  const int lo = lane & 15, hi = lane >> 4;

  const ushort_t* qb = qhp + ((size_t)bh * S_ + row0) * 64;
  const ushort_t* kb = khp + ((size_t)bh * S_ + kt0) * 64;
  const ushort_t* vb = vT + (size_t)bh * 64 * S_ + kt0;
  const float* pb = prev + (size_t)bh * S_ * S_ + (size_t)(row0 + lo) * S_ + kt0;
  float* sb = scores + (size_t)bh * S_ * S_ + (size_t)(row0 + lo) * S_ + kt0;

  // Q B-fragments (q = lo)
  bf16x8 qf0 = *(const bf16x8*)(qb + lo * 64 + hi * 8);
  bf16x8 qf1 = *(const bf16x8*)(qb + lo * 64 + 32 + hi * 8);

  // ---- stage K 512x64 bf16 -> LDS (swizzled src, linear dest), 512 thr ----
#pragma unroll
  for (int i = 0; i < 8; ++i) {
    int u = i * 512 + t;            // 16-byte unit index (0..4095)
    int r = u >> 3;                 // k row (0..511)
    int s = (u & 7) * 16;           // byte within row
    int cb = s ^ ((r & 7) << 4);    // swizzled source byte
    gll16(kb + (size_t)r * 64 + cb / 2, (ushort_t*)lK + u * 8);
  }
  // ---- issue chunk-0 prev loads before the one-time drain ----
  float4 pcur[8];
#pragma unroll
  for (int kf = 0; kf < 8; ++kf)
    pcur[kf] = *(const float4*)(pb + kf * 16 + hi * 4);
  asm volatile("s_waitcnt vmcnt(0)" ::: "memory");
  __syncthreads();

  const int swz = (lo & 7) << 4;
  const char* lkb = (const char*)lK;
  char* pw = (char*)&Plds[w][0];

  f32x4 acco[4];  // acco[dn][p] = O[d = dn*16 + hi*4 + p][q = lo]
#pragma unroll
  for (int dn = 0; dn < 4; ++dn) acco[dn] = f32x4{0.f, 0.f, 0.f, 0.f};
  float m_run = -1e30f, l_run = 0.f;

  for (int c = 0; c < 4; ++c) {
    // ---- V(c) loads (L2; issued BEFORE prev(c+1) => older in queue) ----
    bf16x8 vf[4][4];
#pragma unroll
    for (int kc = 0; kc < 4; ++kc)
#pragma unroll
      for (int dn = 0; dn < 4; ++dn)
        vf[kc][dn] = *(const bf16x8*)(vb + (size_t)(dn * 16 + lo) * S_ +
                                      c * 128 + kc * 32 + hi * 8);
    // ---- issue prev(c+1) (HBM, youngest) ----
    float4 pnext[8];
    if (c < 3) {
#pragma unroll
      for (int kf = 0; kf < 8; ++kf)
        pnext[kf] = *(const float4*)(pb + (c + 1) * 128 + kf * 16 + hi * 4);
    }
    // ---- QK^T from LDS (lgkmcnt only) ----
    f32x4 acc[8];
#pragma unroll
    for (int kf = 0; kf < 8; ++kf) acc[kf] = f32x4{0.f, 0.f, 0.f, 0.f};
#pragma unroll
    for (int kf = 0; kf < 8; ++kf) {
      int krow = c * 128 + kf * 16 + lo;
      bf16x8 k0 = *(const bf16x8*)(lkb + krow * 128 + ((hi * 16) ^ swz));
      bf16x8 k1 = *(const bf16x8*)(lkb + krow * 128 + ((64 + hi * 16) ^ swz));
      acc[kf] = __builtin_amdgcn_mfma_f32_16x16x32_bf16(k0, qf0, acc[kf], 0, 0, 0);
      acc[kf] = __builtin_amdgcn_mfma_f32_16x16x32_bf16(k1, qf1, acc[kf], 0, 0, 0);
    }
    // ---- consume prev(c) (oldest; retires nothing else); store scores ----
    float tmax = -1e30f;
#pragma unroll
    for (int kf = 0; kf < 8; ++kf) {
      acc[kf][0] = acc[kf][0] * 0.125f + pcur[kf].x;
      acc[kf][1] = acc[kf][1] * 0.125f + pcur[kf].y;
      acc[kf][2] = acc[kf][2] * 0.125f + pcur[kf].z;
      acc[kf][3] = acc[kf][3] * 0.125f + pcur[kf].w;
      *(float4*)(sb + c * 128 + kf * 16 + hi * 4) =
          float4{acc[kf][0], acc[kf][1], acc[kf][2], acc[kf][3]};
      tmax = fmaxf(tmax, fmaxf(fmaxf(acc[kf][0], acc[kf][1]), fmaxf(acc[kf][2], acc[kf][3])));
    }
    // ---- online stats + P pack into per-wave LDS ----
    tmax = fmaxf(tmax, __shfl_xor(tmax, 16));
    tmax = fmaxf(tmax, __shfl_xor(tmax, 32));
    float m_new = fmaxf(m_run, tmax);
    float fs = __expf(m_run - m_new);
    float lsum = 0.f;
#pragma unroll
    for (int kf = 0; kf < 8; ++kf) {
      float e0 = __expf(acc[kf][0] - m_new);
      float e1 = __expf(acc[kf][1] - m_new);
      float e2 = __expf(acc[kf][2] - m_new);
      float e3 = __expf(acc[kf][3] - m_new);
      lsum += (e0 + e1) + (e2 + e3);
      u16x4 pk;
      pk.x = f2bf(e0); pk.y = f2bf(e1); pk.z = f2bf(e2); pk.w = f2bf(e3);
      int byte = (lo * 256 + kf * 32 + hi * 8) ^ swz;
      *(u16x4*)(pw + byte) = pk;
    }
    lsum += __shfl_xor(lsum, 16);
    lsum += __shfl_xor(lsum, 32);
    m_run = m_new;
    l_run = l_run * fs + lsum;
    // ---- rescale acco (q = lo: lane-local factor) ----
#pragma unroll
    for (int dn = 0; dn < 4; ++dn)
#pragma unroll
      for (int p = 0; p < 4; ++p) acco[dn][p] *= fs;
    // ---- PV: A = V frag, B = P from LDS; waits V(c) only ----
#pragma unroll
    for (int kc = 0; kc < 4; ++kc) {
      int byte = (lo * 256 + kc * 64 + hi * 16) ^ swz;
      bf16x8 pa = *(const bf16x8*)(pw + byte);
#pragma unroll
      for (int dn = 0; dn < 4; ++dn)
        acco[dn] = __builtin_amdgcn_mfma_f32_16x16x32_bf16(vf[kc][dn], pa, acco[dn], 0, 0, 0);
    }
    if (c < 3) {
#pragma unroll
      for (int kf = 0; kf < 8; ++kf) pcur[kf] = pnext[kf];
    }
  }
  // ---- epilogue: partial O (bf16) + (m, l) stats ----
  ushort_t* ob = Opart + (((size_t)bh * S_ + row0 + lo) * 4 + ct) * 64;
#pragma unroll
  for (int dn = 0; dn < 4; ++dn) {
    u16x4 ov;
#pragma unroll
    for (int p = 0; p < 4; ++p) ov[p] = f2bf(acco[dn][p]);
    *(u16x4*)(ob + dn * 16 + hi * 4) = ov;
  }
  if (hi == 0)
    *(float2*)(pstats + (((size_t)bh * S_ + row0 + lo) * 4 + ct) * 2) =
        float2{m_run, l_run};
}

// ---------------- K3: combine partial O -> ctx ----------------------------
__global__ __launch_bounds__(256) void k_combine(
    const float* __restrict__ pstats,  // [BH][S][4][2]
    const ushort_t* __restrict__ Opart,// [BH][S][4][64]
    ushort_t* __restrict__ ctx) {      // [M_TOK][D]
  const int t = threadIdx.x;
  const int row = blockIdx.x * 64 + (t >> 2);  // bh*S + s
  const int hi4 = t & 3;
  const int bh = row >> 11, s = row & (S_ - 1);

  const float* ps = pstats + (size_t)row * 8;
  float2 st[4];
#pragma unroll
  for (int i = 0; i < 4; ++i) st[i] = *(const float2*)(ps + i * 2);
  float m = fmaxf(fmaxf(st[0].x, st[1].x), fmaxf(st[2].x, st[3].x));
  float den = 0.f;
#pragma unroll
  for (int i = 0; i < 4; ++i) den += st[i].y * __expf(st[i].x - m);
  float sc[4];
#pragma unroll
  for (int i = 0; i < 4; ++i) sc[i] = __expf(st[i].x - m) / den;

  const ushort_t* ob = Opart + (size_t)row * 256 + hi4 * 16;
  float o[16];
#pragma unroll
  for (int j = 0; j < 16; ++j) o[j] = 0.f;
#pragma unroll
  for (int i = 0; i < 4; ++i) {
    bf16x8 a0 = *(const bf16x8*)(ob + i * 64);
    bf16x8 a1 = *(const bf16x8*)(ob + i * 64 + 8);
#pragma unroll
    for (int j = 0; j < 8; ++j) {
      o[j]     += bf2f((ushort_t)a0[j]) * sc[i];
      o[8 + j] += bf2f((ushort_t)a1[j]) * sc[i];
    }
  }
  const int b = bh >> 4, h = bh & 15;
  ushort_t* cp = ctx + (size_t)(b * S_ + s) * D_ + h * 64 + hi4 * 16;
#pragma unroll
  for (int g = 0; g < 4; ++g) {
    u16x4 ov;
#pragma unroll
    for (int p = 0; p < 4; ++p) ov[p] = f2bf(o[g * 4 + p]);
    *(u16x4*)(cp + g * 4) = ov;
  }
}

// ---------------- K4: output GEMM + bias (fp32 out) -----------------------
__global__ __launch_bounds__(256) void k_gemm_out(
    const ushort_t* __restrict__ A,   // ctx [4096][1024]
    const ushort_t* __restrict__ Bt,  // WoutT [1024][1024]
    const float* __restrict__ bias,   // [1024]
    float* __restrict__ out) {
  constexpr int K = 1024;
  __shared__ ushort_t lA[128 * 32];
  __shared__ ushort_t lB[128 * 32];
  const int t = threadIdx.x, lane = t & 63, w = t >> 6;
  const int wm = w >> 1, wn = w & 1;
  const int bm = blockIdx.x & 31, bn = blockIdx.x >> 5;  // 32 x 8

  f32x4 acc[4][4];
#pragma unroll
  for (int i = 0; i < 4; ++i)
#pragma unroll
    for (int j = 0; j < 4; ++j) acc[i][j] = f32x4{0.f, 0.f, 0.f, 0.f};

  const int srow = t >> 2;
  const int scol = (t & 3) * 8;
  for (int k0 = 0; k0 < K; k0 += 32) {
    __syncthreads();
    gll16(A + (size_t)(bm * 128 + srow) * K + k0 + scol, lA + srow * 32 + scol);
    gll16(A + (size_t)(bm * 128 + 64 + srow) * K + k0 + scol, lA + (64 + srow) * 32 + scol);
    gll16(Bt + (size_t)(bn * 128 + srow) * K + k0 + scol, lB + srow * 32 + scol);
    gll16(Bt + (size_t)(bn * 128 + 64 + srow) * K + k0 + scol, lB + (64 + srow) * 32 + scol);
    asm volatile("s_waitcnt vmcnt(0)" ::: "memory");
    __syncthreads();
    bf16x8 af[4], bfr[4];
#pragma unroll
    for (int i = 0; i < 4; ++i)
      af[i] = *(const bf16x8*)(lA + (wm * 64 + i * 16 + (lane & 15)) * 32 + (lane >> 4) * 8);
#pragma unroll
    for (int j = 0; j < 4; ++j)
      bfr[j] = *(const bf16x8*)(lB + (wn * 64 + j * 16 + (lane & 15)) * 32 + (lane >> 4) * 8);
#pragma unroll
    for (int i = 0; i < 4; ++i)
#pragma unroll
      for (int j = 0; j < 4; ++j)
        acc[i][j] = __builtin_amdgcn_mfma_f32_16x16x32_bf16(af[i], bfr[j], acc[i][j], 0, 0, 0);
  }
#pragma unroll
  for (int i = 0; i < 4; ++i) {
#pragma unroll
    for (int j = 0; j < 4; ++j) {
#pragma unroll
      for (int p = 0; p < 4; ++p) {
        int row = bm * 128 + wm * 64 + i * 16 + (lane >> 4) * 4 + p;
        int col = bn * 128 + wn * 64 + j * 16 + (lane & 15);
        out[(size_t)row * 1024 + col] = acc[i][j][p] + bias[col];
      }
    }
  }
}

extern "C" void kernel_launch(void* const* d_in, const int* in_sizes, int n_in,
                              void* d_out, int out_size, void* d_ws, size_t ws_size,
                              hipStream_t stream) {
  (void)in_sizes; (void)n_in; (void)out_size; (void)ws_size;
  const float* Q     = (const float*)d_in[0];
  const float* prev  = (const float*)d_in[1];
  const float* W_qkv = (const float*)d_in[2];
  const float* b_qkv = (const float*)d_in[3];
  const float* W_out = (const float*)d_in[4];
  const float* b_out = (const float*)d_in[5];
  float* out = (float*)d_out;
  float* scores_out = out + (size_t)M_TOK * D_;  // output first, then scores

  char* ws = (char*)d_ws;
  ushort_t* Qb    = (ushort_t*)(ws + (size_t)0);          // 8 MB (dead after QKV)
  ushort_t* WqkvT = (ushort_t*)(ws + ((size_t)8  << 20)); // 6 MB
  ushort_t* WoutT = (ushort_t*)(ws + ((size_t)14 << 20)); // 2 MB
  ushort_t* qh    = (ushort_t*)(ws + ((size_t)16 << 20)); // 8 MB
  ushort_t* kh    = (ushort_t*)(ws + ((size_t)24 << 20)); // 8 MB
  ushort_t* vT    = (ushort_t*)(ws + ((size_t)32 << 20)); // 8 MB
  ushort_t* ctx   = (ushort_t*)(ws + ((size_t)40 << 20)); // 8 MB
  ushort_t* Opart = (ushort_t*)(ws + ((size_t)48 << 20)); // 32 MB -> 80 MB total
  float*    pstats = (float*)Qb;  // 2 MB, aliases Qb (dead after k_gemm_qkv)

  k_cvt_q<<<4096, 256, 0, stream>>>(Q, Qb);
  k_transpose_cvt<<<dim3(96, 32), 256, 0, stream>>>(W_qkv, WqkvT, 1024, 3072);
  k_transpose_cvt<<<dim3(32, 32), 256, 0, stream>>>(W_out, WoutT, 1024, 1024);
  k_gemm_qkv<<<768, 256, 0, stream>>>(Qb, WqkvT, b_qkv, qh, kh, vT);
  k_scores_pv<<<2048, 512, 0, stream>>>(qh, kh, vT, prev, scores_out, pstats, Opart);
  k_combine<<<1024, 256, 0, stream>>>(pstats, Opart, ctx);
  k_gemm_out<<<256, 256, 0, stream>>>(ctx, WoutT, b_out, out);
}